// Round 13
// baseline (36.982 us; speedup 1.0000x reference)
//
#include <hip/hip_runtime.h>
#include <hip/hip_bf16.h>
#include <math.h>

#define TB 256
#define TILES 2
#define PI_F 3.14159265358979323846f

typedef __attribute__((ext_vector_type(8))) short short8;
typedef __attribute__((ext_vector_type(4))) float f32x4;
typedef __attribute__((ext_vector_type(2))) float f32x2;

union Frag { short8 v; ushort u[8]; uint w[4]; };

__device__ __forceinline__ uint pk2(float a, float b) {
    union { __hip_bfloat162 h; uint u; } cv;
    cv.h = __float22bfloat162_rn(make_float2(a, b));   // packed RNE cvt
    return cv.u;
}

// non-temporal 16B load (read-once stream: no L2 allocate)
__device__ __forceinline__ float4 ntld(const float* p) {
    f32x4 v = __builtin_nontemporal_load((const f32x4*)p);
    return make_float4(v.x, v.y, v.z, v.w);
}
// non-temporal 8B store (write-once stream)
__device__ __forceinline__ void ntst(float* p, float a, float b) {
    f32x2 v; v.x = a; v.y = b;
    __builtin_nontemporal_store(v, (f32x2*)p);
}

// x path: hi-only bf16 (4 packed cvts per 8 floats)
__device__ __forceinline__ void cvt_hi(const float4& p0, const float4& p1, Frag& hi) {
    hi.w[0] = pk2(p0.x, p0.y); hi.w[1] = pk2(p0.z, p0.w);
    hi.w[2] = pk2(p1.x, p1.y); hi.w[3] = pk2(p1.z, p1.w);
}

// Wp path (one-time): hi + residual lo
__device__ __forceinline__ void cvt8(const float4& p0, const float4& p1, Frag& hi, Frag& lo) {
    float f[8] = {p0.x, p0.y, p0.z, p0.w, p1.x, p1.y, p1.z, p1.w};
    #pragma unroll
    for (int e = 0; e < 4; ++e) hi.w[e] = pk2(f[2 * e], f[2 * e + 1]);
    #pragma unroll
    for (int e = 0; e < 4; ++e) {
        float r0 = f[2 * e]     - __uint_as_float(hi.w[e] << 16);
        float r1 = f[2 * e + 1] - __uint_as_float(hi.w[e] & 0xffff0000u);
        lo.w[e] = pk2(r0, r1);
    }
}

__device__ __forceinline__ float fast_tanh(float p) {
    float t = __expf(2.0f * p);
    return 1.0f - __fdividef(2.0f, t + 1.0f);
}

__global__ __launch_bounds__(TB, 3) void sqru_fused_kernel(
    const float* __restrict__ x, const float* __restrict__ Wp,
    const float* __restrict__ bp, const float* __restrict__ qw,
    const float* __restrict__ W1, const float* __restrict__ b1,
    const float* __restrict__ W2, const float* __restrict__ b2,
    float* __restrict__ out, int nrows)
{
    __shared__ ushort whi[512 * 8];        // 8 KB Wp hi frags [(s*4+kbi)*16+jc]
    __shared__ ushort wlo[512 * 8];        // 8 KB Wp lo frags
    __shared__ float  proj_s[4][16 * 17];  // wave-private transpose
    __shared__ float  qbuf[4][16][8];
    __shared__ float  w1_s[32 * 8];
    __shared__ float  w2_s[10 * 32];
    __shared__ float  b1_s[32];
    __shared__ float  b2_s[10];
    __shared__ float  rot_s[8][3][6];

    const int t   = threadIdx.x;
    const int w   = t >> 6;
    const int l   = t & 63;
    const int jc  = l & 15;     // M-row (batch row) and N-col (proj out) index
    const int kbi = l >> 4;     // K sub-group
    const int gw  = blockIdx.x * 4 + w;
    const int tile0 = gw * TILES;

    int r0 = tile0 * 16 + jc;       if (r0 >= nrows) r0 = nrows - 1;
    int r1 = (tile0 + 1) * 16 + jc; if (r1 >= nrows) r1 = nrows - 1;
    // FULL-LINE mapping: lane (jc,kbi) reads 16B at row*1KB + s*128 + kbi*16 (and +64)
    const float* xp0 = x + (size_t)r0 * 256 + kbi * 4;
    const float* xp1 = x + (size_t)r1 * 256 + kbi * 4;

    // ---- ring prologue: ALL of tile0 (8 K-steps) in flight before staging ----
    float4 xa0 = ntld(xp0 +   0), xb0 = ntld(xp0 +  16);
    float4 xa1 = ntld(xp0 +  32), xb1 = ntld(xp0 +  48);
    float4 xa2 = ntld(xp0 +  64), xb2 = ntld(xp0 +  80);
    float4 xa3 = ntld(xp0 +  96), xb3 = ntld(xp0 + 112);
    float4 xa4 = ntld(xp0 + 128), xb4 = ntld(xp0 + 144);
    float4 xa5 = ntld(xp0 + 160), xb5 = ntld(xp0 + 176);
    float4 xa6 = ntld(xp0 + 192), xb6 = ntld(xp0 + 208);
    float4 xa7 = ntld(xp0 + 224), xb7 = ntld(xp0 + 240);

    // ---- one-time weight staging (temporal: reused per block) ----
    if (t < 64) ((float4*)w1_s)[t] = ((const float4*)W1)[t];
    if (t < 80) ((float4*)w2_s)[t] = ((const float4*)W2)[t];
    if (t < 32) b1_s[t] = b1[t];
    if (t < 10) b2_s[t] = b2[t];
    if (t < 24) {
        int u = t / 3, l2 = t % 3;
        float q0 = qw[u * 9 + l2 * 3 + 0];
        float q1 = qw[u * 9 + l2 * 3 + 1];
        float q2 = qw[u * 9 + l2 * 3 + 2];
        rot_s[u][l2][0] = cosf(q0);        rot_s[u][l2][1] = sinf(q0);
        rot_s[u][l2][2] = cosf(0.5f * q1); rot_s[u][l2][3] = sinf(0.5f * q1);
        rot_s[u][l2][4] = cosf(q2);        rot_s[u][l2][5] = sinf(q2);
    }
    // Wp frags with the SAME permuted element order: e0..3 <- k=kb*4.., e4..7 <- k=16+kb*4..
    #pragma unroll
    for (int ff = 0; ff < 2; ++ff) {
        int f = t + ff * 256;
        int jc2 = f & 15, kb2 = (f >> 4) & 3, s2 = f >> 6;
        const float* wp = Wp + jc2 * 256 + s2 * 32 + kb2 * 4;
        float4 p0 = *(const float4*)wp;
        float4 p1 = *(const float4*)(wp + 16);
        Frag h, lo2;
        cvt8(p0, p1, h, lo2);
        ((short8*)whi)[f] = h.v;
        ((short8*)wlo)[f] = lo2.v;
    }
    __syncthreads();   // only barrier in the kernel

    const float bpj  = bp[jc];
    const int   srow = l >> 2;
    const int   s4   = l & 3;
    const short8* whi_f = (const short8*)whi;
    const short8* wlo_f = (const short8*)wlo;

    auto do_tile = [&](const float* xpn, int tile, bool refill) {
        f32x4 accm = {bpj, bpj, bpj, bpj};
        f32x4 accc = {0.0f, 0.0f, 0.0f, 0.0f};

        // 8 static K-steps; each consumes its slot, then refills it from next tile
        #define STEP(S, XA, XB)                                                     \
        {                                                                           \
            Frag ah; cvt_hi(XA, XB, ah);                                            \
            if (refill) {                                                           \
                XA = ntld(xpn + (S) * 32);                                          \
                XB = ntld(xpn + (S) * 32 + 16);                                     \
            }                                                                       \
            Frag bh, bl;                                                            \
            bh.v = whi_f[((S) * 4 + kbi) * 16 + jc];                                \
            bl.v = wlo_f[((S) * 4 + kbi) * 16 + jc];                                \
            accm = __builtin_amdgcn_mfma_f32_16x16x32_bf16(ah.v, bh.v, accm, 0, 0, 0); \
            accc = __builtin_amdgcn_mfma_f32_16x16x32_bf16(ah.v, bl.v, accc, 0, 0, 0); \
        }
        STEP(0, xa0, xb0)
        STEP(1, xa1, xb1)
        STEP(2, xa2, xb2)
        STEP(3, xa3, xb3)
        STEP(4, xa4, xb4)
        STEP(5, xa5, xb5)
        STEP(6, xa6, xb6)
        STEP(7, xa7, xb7)
        #undef STEP

        // ---- transpose C[row=kbi*4+r][col=jc] via wave-private LDS ----
        #pragma unroll
        for (int r = 0; r < 4; ++r)
            proj_s[w][(kbi * 4 + r) * 17 + jc] = accm[r] + accc[r];

        float4 pv = *(const float4*)&proj_s[w][srow * 17 + s4 * 4];

        // ---- unit-split circuit: 4 lanes/row, 2 units each ----
        float qv[2];
        #pragma unroll
        for (int uu = 0; uu < 2; ++uu) {
            const int u = 2 * s4 + uu;
            float p0 = (uu == 0) ? pv.x : pv.z;
            float p1 = (uu == 0) ? pv.y : pv.w;
            float th0 = fast_tanh(p0);
            float th1 = fast_tanh(p1);
            float c  = __cosf(0.5f * PI_F * th0);
            float s  = __sinf(0.5f * PI_F * th0);
            float zr = __cosf(PI_F * th1);
            float zi = __sinf(PI_F * th1);

            float ar = c, ai = 0.0f, br = s, bi = 0.0f;
            #pragma unroll
            for (int l2 = 0; l2 < 3; ++l2) {
                if (l2 > 0) {
                    float nar = c * ar - s * br, nai = c * ai - s * bi;
                    float nbr = s * ar + c * br, nbi = s * ai + c * bi;
                    ar = nar; ai = nai; br = nbr; bi = nbi;
                }
                float e0r = rot_s[u][l2][0], e0i = rot_s[u][l2][1];
                float p2r = zr * e0r - zi * e0i;
                float p2q = zr * e0i + zi * e0r;
                float nbr = br * p2r - bi * p2q, nbi = br * p2q + bi * p2r;
                br = nbr; bi = nbi;
                float c1 = rot_s[u][l2][2], s1 = rot_s[u][l2][3];
                float tar = c1 * ar - s1 * br, tai = c1 * ai - s1 * bi;
                float tbr = s1 * ar + c1 * br, tbi = s1 * ai + c1 * bi;
                ar = tar; ai = tai; br = tbr; bi = tbi;
                if (l2 < 2) {
                    float e2r = rot_s[u][l2][4], e2i = rot_s[u][l2][5];
                    float ubr = br * e2r - bi * e2i, ubi = br * e2i + bi * e2r;
                    br = ubr; bi = ubi;
                }
            }
            qv[uu] = (ar * ar + ai * ai) - (br * br + bi * bi);
        }

        float* qb = &qbuf[w][srow][0];
        *(float2*)(qb + 2 * s4) = make_float2(qv[0], qv[1]);
        float4 qa  = *(const float4*)(qb + 0);
        float4 qbv = *(const float4*)(qb + 4);

        // ---- head: lane covers j = s4*8..s4*8+7, 4-lane reduce ----
        float ov[10];
        #pragma unroll
        for (int c2 = 0; c2 < 10; ++c2) ov[c2] = 0.0f;
        #pragma unroll
        for (int jj = 0; jj < 8; ++jj) {
            const int j = s4 * 8 + jj;
            float h = b1_s[j];
            h = fmaf(qa.x,  w1_s[j * 8 + 0], h);
            h = fmaf(qa.y,  w1_s[j * 8 + 1], h);
            h = fmaf(qa.z,  w1_s[j * 8 + 2], h);
            h = fmaf(qa.w,  w1_s[j * 8 + 3], h);
            h = fmaf(qbv.x, w1_s[j * 8 + 4], h);
            h = fmaf(qbv.y, w1_s[j * 8 + 5], h);
            h = fmaf(qbv.z, w1_s[j * 8 + 6], h);
            h = fmaf(qbv.w, w1_s[j * 8 + 7], h);
            h = fmaxf(h, 0.0f);
            #pragma unroll
            for (int c2 = 0; c2 < 10; ++c2) ov[c2] = fmaf(h, w2_s[c2 * 32 + j], ov[c2]);
        }
        #pragma unroll
        for (int c2 = 0; c2 < 10; ++c2) {
            ov[c2] += __shfl_xor(ov[c2], 1);
            ov[c2] += __shfl_xor(ov[c2], 2);
            ov[c2] += b2_s[c2];
        }

        const int orow = tile * 16 + srow;
        if (orow < nrows) {
            float* op = out + (size_t)orow * 10;
            float lo = (s4 == 0) ? ov[0] : (s4 == 1) ? ov[2] : (s4 == 2) ? ov[4] : ov[6];
            float hi = (s4 == 0) ? ov[1] : (s4 == 1) ? ov[3] : (s4 == 2) ? ov[5] : ov[7];
            ntst(op + 2 * s4, lo, hi);
            if (s4 == 0) ntst(op + 8, ov[8], ov[9]);
        }
    };

    do_tile(xp1, tile0, true);        // compute tile0, stream in tile1 behind it
    do_tile(xp1, tile0 + 1, false);   // compute tile1, no refill
}

extern "C" void kernel_launch(void* const* d_in, const int* in_sizes, int n_in,
                              void* d_out, int out_size, void* d_ws, size_t ws_size,
                              hipStream_t stream) {
    const float* x  = (const float*)d_in[0];
    const float* Wp = (const float*)d_in[1];
    const float* bp = (const float*)d_in[2];
    const float* qw = (const float*)d_in[3];
    const float* W1 = (const float*)d_in[4];
    const float* b1 = (const float*)d_in[5];
    const float* W2 = (const float*)d_in[6];
    const float* b2 = (const float*)d_in[7];
    float* out = (float*)d_out;

    const int nrows = in_sizes[0] / 256;
    const int rows_per_block = 16 * TILES * 4;   // 128
    const int nblocks = (nrows + rows_per_block - 1) / rows_per_block;
    sqru_fused_kernel<<<nblocks, TB, 0, stream>>>(x, Wp, bp, qw, W1, b1, W2, b2, out, nrows);
}

// Round 14
// 36.622 us; speedup vs baseline: 1.0098x; 1.0098x over previous
//
#include <hip/hip_runtime.h>
#include <hip/hip_bf16.h>
#include <math.h>

#define TB 256
#define TILES 4
#define PI_F 3.14159265358979323846f

typedef __attribute__((ext_vector_type(8))) short short8;
typedef __attribute__((ext_vector_type(4))) float f32x4;

union Frag { short8 v; ushort u[8]; uint w[4]; };

__device__ __forceinline__ uint pk2(float a, float b) {
    union { __hip_bfloat162 h; uint u; } cv;
    cv.h = __float22bfloat162_rn(make_float2(a, b));   // packed RNE cvt
    return cv.u;
}

// Wp path (one-time): hi + residual lo
__device__ __forceinline__ void cvt8(const float4& p0, const float4& p1, Frag& hi, Frag& lo) {
    float f[8] = {p0.x, p0.y, p0.z, p0.w, p1.x, p1.y, p1.z, p1.w};
    #pragma unroll
    for (int e = 0; e < 4; ++e) hi.w[e] = pk2(f[2 * e], f[2 * e + 1]);
    #pragma unroll
    for (int e = 0; e < 4; ++e) {
        float r0 = f[2 * e]     - __uint_as_float(hi.w[e] << 16);
        float r1 = f[2 * e + 1] - __uint_as_float(hi.w[e] & 0xffff0000u);
        lo.w[e] = pk2(r0, r1);
    }
}

__device__ __forceinline__ float fast_tanh(float p) {
    float t = __expf(2.0f * p);
    return 1.0f - __fdividef(2.0f, t + 1.0f);
}

__global__ __launch_bounds__(TB, 2) void sqru_fused_kernel(
    const float* __restrict__ x, const float* __restrict__ Wp,
    const float* __restrict__ bp, const float* __restrict__ qw,
    const float* __restrict__ W1, const float* __restrict__ b1,
    const float* __restrict__ W2, const float* __restrict__ b2,
    float* __restrict__ out, int nrows)
{
    __shared__ ushort xtile[4][2][16 * 256];   // 64 KB: per-wave double-buffered bf16 tiles
    __shared__ float  proj_s[4][16 * 17];      // wave-private transpose
    __shared__ float  qbuf[4][16][8];
    __shared__ float  w1_s[32 * 8];
    __shared__ float  w2_s[10 * 32];
    __shared__ float  b1_s[32];
    __shared__ float  b2_s[10];
    __shared__ float  rot_s[8][3][6];

    const int t   = threadIdx.x;
    const int w   = t >> 6;
    const int l   = t & 63;
    const int jc  = l & 15;     // M-row (batch row) and N-col (proj out) index
    const int kbi = l >> 4;     // K sub-group
    const int gw  = blockIdx.x * 4 + w;
    const int tile0 = gw * TILES;

    // ---- x staging helpers: copy-kernel-shaped loads (1KB/instr, full 128B lines) ----
    auto ldrow = [&](int tile, int i) -> float4 {
        int r = tile * 16 + i;
        r = (r < nrows) ? r : (nrows - 1);
        return *(const float4*)(x + (size_t)r * 256 + l * 4);
    };
    char* xt = (char*)&xtile[w][0][0];         // buf b at + b*8192 bytes
    auto wrow = [&](char* base, int i, const float4& v) {
        uint2 pv;
        pv.x = pk2(v.x, v.y);
        pv.y = pk2(v.z, v.w);
        // chunk (16B) index l>>1, stored at (l>>1)^(i&7); half = l&1
        *(uint2*)(base + i * 512 + ((((l >> 1) ^ (i & 7))) << 4) + ((l & 1) << 3)) = pv;
    };

    // ---- prologue: stage tile0 -> buf0 (8 loads in flight per phase) ----
    {
        float4 v0 = ldrow(tile0, 0), v1 = ldrow(tile0, 1), v2 = ldrow(tile0, 2), v3 = ldrow(tile0, 3);
        float4 v4 = ldrow(tile0, 4), v5 = ldrow(tile0, 5), v6 = ldrow(tile0, 6), v7 = ldrow(tile0, 7);
        wrow(xt, 0, v0); wrow(xt, 1, v1); wrow(xt, 2, v2); wrow(xt, 3, v3);
        v0 = ldrow(tile0,  8); v1 = ldrow(tile0,  9); v2 = ldrow(tile0, 10); v3 = ldrow(tile0, 11);
        wrow(xt, 4, v4); wrow(xt, 5, v5); wrow(xt, 6, v6); wrow(xt, 7, v7);
        v4 = ldrow(tile0, 12); v5 = ldrow(tile0, 13); v6 = ldrow(tile0, 14); v7 = ldrow(tile0, 15);
        wrow(xt,  8, v0); wrow(xt,  9, v1); wrow(xt, 10, v2); wrow(xt, 11, v3);
        wrow(xt, 12, v4); wrow(xt, 13, v5); wrow(xt, 14, v6); wrow(xt, 15, v7);
    }

    // ---- one-time small-weight staging (only shared state needing the barrier) ----
    if (t < 64) ((float4*)w1_s)[t] = ((const float4*)W1)[t];
    if (t < 80) ((float4*)w2_s)[t] = ((const float4*)W2)[t];
    if (t < 32) b1_s[t] = b1[t];
    if (t < 10) b2_s[t] = b2[t];
    if (t < 24) {
        int u = t / 3, l2 = t % 3;
        float q0 = qw[u * 9 + l2 * 3 + 0];
        float q1 = qw[u * 9 + l2 * 3 + 1];
        float q2 = qw[u * 9 + l2 * 3 + 2];
        rot_s[u][l2][0] = cosf(q0);        rot_s[u][l2][1] = sinf(q0);
        rot_s[u][l2][2] = cosf(0.5f * q1); rot_s[u][l2][3] = sinf(0.5f * q1);
        rot_s[u][l2][4] = cosf(q2);        rot_s[u][l2][5] = sinf(q2);
    }

    // ---- Wp -> per-lane bf16 hi/lo B-fragments in REGISTERS (R7-proven) ----
    Frag whi_r[8], wlo_r[8];
    {
        const float* wpb = Wp + jc * 256 + kbi * 8;
        #pragma unroll
        for (int s = 0; s < 8; ++s) {
            float4 w0 = *(const float4*)(wpb + s * 32);
            float4 w1v = *(const float4*)(wpb + s * 32 + 4);
            cvt8(w0, w1v, whi_r[s], wlo_r[s]);
        }
    }
    const float bpj = bp[jc];
    __syncthreads();   // only barrier in the kernel

    const int srow = l >> 2;
    const int s4   = l & 3;
    const int rdk  = (jc & 7);

    for (int tt = 0; tt < TILES; ++tt) {
        const int  tile = tile0 + tt;
        const bool pf   = (tt < TILES - 1);
        const int  nt   = tile + 1;
        char* cb = xt + (tt & 1) * 8192;          // current buf
        char* nb = xt + ((tt + 1) & 1) * 8192;    // next buf

        f32x4 accm = {bpj, bpj, bpj, bpj};
        f32x4 accc = {0.0f, 0.0f, 0.0f, 0.0f};
        float4 pA0, pA1, pB0, pB1;

        #define STEP(S)                                                              \
        {                                                                            \
            Frag ah;                                                                 \
            ah.v = *(const short8*)(cb + jc * 512 + ((((S) * 4 + kbi) ^ rdk) << 4)); \
            accm = __builtin_amdgcn_mfma_f32_16x16x32_bf16(ah.v, whi_r[S].v, accm, 0, 0, 0); \
            accc = __builtin_amdgcn_mfma_f32_16x16x32_bf16(ah.v, wlo_r[S].v, accc, 0, 0, 0); \
        }
        // 8 K-steps with 2-pair skewed staging of the NEXT tile (max 4 loads live)
        if (pf) { pA0 = ldrow(nt, 0); pA1 = ldrow(nt, 1); }
        STEP(0)
        if (pf) { pB0 = ldrow(nt, 2); pB1 = ldrow(nt, 3); }
        STEP(1)
        if (pf) { wrow(nb, 0, pA0); wrow(nb, 1, pA1); pA0 = ldrow(nt, 4); pA1 = ldrow(nt, 5); }
        STEP(2)
        if (pf) { wrow(nb, 2, pB0); wrow(nb, 3, pB1); pB0 = ldrow(nt, 6); pB1 = ldrow(nt, 7); }
        STEP(3)
        if (pf) { wrow(nb, 4, pA0); wrow(nb, 5, pA1); pA0 = ldrow(nt, 8); pA1 = ldrow(nt, 9); }
        STEP(4)
        if (pf) { wrow(nb, 6, pB0); wrow(nb, 7, pB1); pB0 = ldrow(nt, 10); pB1 = ldrow(nt, 11); }
        STEP(5)
        if (pf) { wrow(nb, 8, pA0); wrow(nb, 9, pA1); pA0 = ldrow(nt, 12); pA1 = ldrow(nt, 13); }
        STEP(6)
        if (pf) { wrow(nb, 10, pB0); wrow(nb, 11, pB1); pB0 = ldrow(nt, 14); pB1 = ldrow(nt, 15); }
        STEP(7)
        #undef STEP

        // ---- transpose C[row=kbi*4+r][col=jc] via wave-private LDS ----
        #pragma unroll
        for (int r = 0; r < 4; ++r)
            proj_s[w][(kbi * 4 + r) * 17 + jc] = accm[r] + accc[r];

        float4 pv = *(const float4*)&proj_s[w][srow * 17 + s4 * 4];

        // ---- unit-split circuit: 4 lanes/row, 2 units each ----
        float qv[2];
        #pragma unroll
        for (int uu = 0; uu < 2; ++uu) {
            const int u = 2 * s4 + uu;
            float p0 = (uu == 0) ? pv.x : pv.z;
            float p1 = (uu == 0) ? pv.y : pv.w;
            float th0 = fast_tanh(p0);
            float th1 = fast_tanh(p1);
            float c  = __cosf(0.5f * PI_F * th0);
            float s  = __sinf(0.5f * PI_F * th0);
            float zr = __cosf(PI_F * th1);
            float zi = __sinf(PI_F * th1);

            float ar = c, ai = 0.0f, br = s, bi = 0.0f;
            #pragma unroll
            for (int l2 = 0; l2 < 3; ++l2) {
                if (l2 > 0) {
                    float nar = c * ar - s * br, nai = c * ai - s * bi;
                    float nbr = s * ar + c * br, nbi = s * ai + c * bi;
                    ar = nar; ai = nai; br = nbr; bi = nbi;
                }
                float e0r = rot_s[u][l2][0], e0i = rot_s[u][l2][1];
                float p2r = zr * e0r - zi * e0i;
                float p2q = zr * e0i + zi * e0r;
                float nbr = br * p2r - bi * p2q, nbi = br * p2q + bi * p2r;
                br = nbr; bi = nbi;
                float c1 = rot_s[u][l2][2], s1 = rot_s[u][l2][3];
                float tar = c1 * ar - s1 * br, tai = c1 * ai - s1 * bi;
                float tbr = s1 * ar + c1 * br, tbi = s1 * ai + c1 * bi;
                ar = tar; ai = tai; br = tbr; bi = tbi;
                if (l2 < 2) {
                    float e2r = rot_s[u][l2][4], e2i = rot_s[u][l2][5];
                    float ubr = br * e2r - bi * e2i, ubi = br * e2i + bi * e2r;
                    br = ubr; bi = ubi;
                }
            }
            qv[uu] = (ar * ar + ai * ai) - (br * br + bi * bi);
        }

        float* qb = &qbuf[w][srow][0];
        *(float2*)(qb + 2 * s4) = make_float2(qv[0], qv[1]);
        float4 qa  = *(const float4*)(qb + 0);
        float4 qbv = *(const float4*)(qb + 4);

        // ---- head: lane covers j = s4*8..s4*8+7, 4-lane reduce ----
        float ov[10];
        #pragma unroll
        for (int c2 = 0; c2 < 10; ++c2) ov[c2] = 0.0f;
        #pragma unroll
        for (int jj = 0; jj < 8; ++jj) {
            const int j = s4 * 8 + jj;
            float h = b1_s[j];
            h = fmaf(qa.x,  w1_s[j * 8 + 0], h);
            h = fmaf(qa.y,  w1_s[j * 8 + 1], h);
            h = fmaf(qa.z,  w1_s[j * 8 + 2], h);
            h = fmaf(qa.w,  w1_s[j * 8 + 3], h);
            h = fmaf(qbv.x, w1_s[j * 8 + 4], h);
            h = fmaf(qbv.y, w1_s[j * 8 + 5], h);
            h = fmaf(qbv.z, w1_s[j * 8 + 6], h);
            h = fmaf(qbv.w, w1_s[j * 8 + 7], h);
            h = fmaxf(h, 0.0f);
            #pragma unroll
            for (int c2 = 0; c2 < 10; ++c2) ov[c2] = fmaf(h, w2_s[c2 * 32 + j], ov[c2]);
        }
        #pragma unroll
        for (int c2 = 0; c2 < 10; ++c2) {
            ov[c2] += __shfl_xor(ov[c2], 1);
            ov[c2] += __shfl_xor(ov[c2], 2);
            ov[c2] += b2_s[c2];
        }

        const int orow = tile * 16 + srow;
        if (orow < nrows) {
            float2* op = (float2*)(out + (size_t)orow * 10);
            float lo = (s4 == 0) ? ov[0] : (s4 == 1) ? ov[2] : (s4 == 2) ? ov[4] : ov[6];
            float hi = (s4 == 0) ? ov[1] : (s4 == 1) ? ov[3] : (s4 == 2) ? ov[5] : ov[7];
            op[s4] = make_float2(lo, hi);
            if (s4 == 0) op[4] = make_float2(ov[8], ov[9]);
        }

        // last 4 rows of next tile: loads had the whole epilogue to land
        if (pf) { wrow(nb, 12, pA0); wrow(nb, 13, pA1); wrow(nb, 14, pB0); wrow(nb, 15, pB1); }
    }
}

extern "C" void kernel_launch(void* const* d_in, const int* in_sizes, int n_in,
                              void* d_out, int out_size, void* d_ws, size_t ws_size,
                              hipStream_t stream) {
    const float* x  = (const float*)d_in[0];
    const float* Wp = (const float*)d_in[1];
    const float* bp = (const float*)d_in[2];
    const float* qw = (const float*)d_in[3];
    const float* W1 = (const float*)d_in[4];
    const float* b1 = (const float*)d_in[5];
    const float* W2 = (const float*)d_in[6];
    const float* b2 = (const float*)d_in[7];
    float* out = (float*)d_out;

    const int nrows = in_sizes[0] / 256;
    const int rows_per_block = 16 * TILES * 4;   // 256
    const int nblocks = (nrows + rows_per_block - 1) / rows_per_block;
    sqru_fused_kernel<<<nblocks, TB, 0, stream>>>(x, Wp, bp, qw, W1, b1, W2, b2, out, nrows);
}

// Round 15
// 34.432 us; speedup vs baseline: 1.0741x; 1.0636x over previous
//
#include <hip/hip_runtime.h>
#include <hip/hip_bf16.h>
#include <math.h>

#define TB 256
#define TILES 4
#define PI_F 3.14159265358979323846f

typedef __attribute__((ext_vector_type(8))) short short8;
typedef __attribute__((ext_vector_type(4))) float f32x4;

union Frag { short8 v; ushort u[8]; uint w[4]; };

__device__ __forceinline__ uint pk2(float a, float b) {
    union { __hip_bfloat162 h; uint u; } cv;
    cv.h = __float22bfloat162_rn(make_float2(a, b));   // packed RNE cvt
    return cv.u;
}

// x path: hi-only bf16 (4 packed cvts per 8 floats)
__device__ __forceinline__ void cvt_hi(const float4& p0, const float4& p1, Frag& hi) {
    hi.w[0] = pk2(p0.x, p0.y); hi.w[1] = pk2(p0.z, p0.w);
    hi.w[2] = pk2(p1.x, p1.y); hi.w[3] = pk2(p1.z, p1.w);
}

// Wp path (one-time): hi + residual lo
__device__ __forceinline__ void cvt8(const float4& p0, const float4& p1, Frag& hi, Frag& lo) {
    float f[8] = {p0.x, p0.y, p0.z, p0.w, p1.x, p1.y, p1.z, p1.w};
    #pragma unroll
    for (int e = 0; e < 4; ++e) hi.w[e] = pk2(f[2 * e], f[2 * e + 1]);
    #pragma unroll
    for (int e = 0; e < 4; ++e) {
        float r0 = f[2 * e]     - __uint_as_float(hi.w[e] << 16);
        float r1 = f[2 * e + 1] - __uint_as_float(hi.w[e] & 0xffff0000u);
        lo.w[e] = pk2(r0, r1);
    }
}

__device__ __forceinline__ float fast_tanh(float p) {
    float t = __expf(2.0f * p);
    return 1.0f - __fdividef(2.0f, t + 1.0f);
}

__global__ __launch_bounds__(TB, 3) void sqru_fused_kernel(
    const float* __restrict__ x, const float* __restrict__ Wp,
    const float* __restrict__ bp, const float* __restrict__ qw,
    const float* __restrict__ W1, const float* __restrict__ b1,
    const float* __restrict__ W2, const float* __restrict__ b2,
    float* __restrict__ out, int nrows)
{
    __shared__ ushort whi[512 * 8];        // 8 KB Wp hi frags [(s*4+kbi)*16+jc]
    __shared__ ushort wlo[512 * 8];        // 8 KB Wp lo frags
    __shared__ float  proj_s[4][16 * 17];  // wave-private transpose
    __shared__ float  qbuf[4][16][8];
    __shared__ float  w1_s[32 * 8];
    __shared__ float  w2_s[10 * 32];
    __shared__ float  b1_s[32];
    __shared__ float  b2_s[10];
    __shared__ float  rot_s[8][3][6];

    const int t   = threadIdx.x;
    const int w   = t >> 6;
    const int l   = t & 63;
    const int jc  = l & 15;     // M-row (batch row) and N-col (proj out) index
    const int kbi = l >> 4;     // K sub-group
    const int gw  = blockIdx.x * 4 + w;
    const int tile0 = gw * TILES;

    int r0 = tile0 * 16 + jc;       if (r0 >= nrows) r0 = nrows - 1;
    int r1 = (tile0 + 1) * 16 + jc; if (r1 >= nrows) r1 = nrows - 1;
    int r2 = (tile0 + 2) * 16 + jc; if (r2 >= nrows) r2 = nrows - 1;
    int r3 = (tile0 + 3) * 16 + jc; if (r3 >= nrows) r3 = nrows - 1;
    // FULL-LINE mapping: lane (jc,kbi) reads 16B at row*1KB + s*128 + kbi*16 (and +64)
    const float* xp0 = x + (size_t)r0 * 256 + kbi * 4;
    const float* xp1 = x + (size_t)r1 * 256 + kbi * 4;
    const float* xp2 = x + (size_t)r2 * 256 + kbi * 4;
    const float* xp3 = x + (size_t)r3 * 256 + kbi * 4;

    // ---- ring prologue: ALL of tile0 (8 K-steps) in flight before staging ----
    float4 xa0 = *(const float4*)(xp0 +   0), xb0 = *(const float4*)(xp0 +  16);
    float4 xa1 = *(const float4*)(xp0 +  32), xb1 = *(const float4*)(xp0 +  48);
    float4 xa2 = *(const float4*)(xp0 +  64), xb2 = *(const float4*)(xp0 +  80);
    float4 xa3 = *(const float4*)(xp0 +  96), xb3 = *(const float4*)(xp0 + 112);
    float4 xa4 = *(const float4*)(xp0 + 128), xb4 = *(const float4*)(xp0 + 144);
    float4 xa5 = *(const float4*)(xp0 + 160), xb5 = *(const float4*)(xp0 + 176);
    float4 xa6 = *(const float4*)(xp0 + 192), xb6 = *(const float4*)(xp0 + 208);
    float4 xa7 = *(const float4*)(xp0 + 224), xb7 = *(const float4*)(xp0 + 240);

    // ---- one-time weight staging ----
    if (t < 64) ((float4*)w1_s)[t] = ((const float4*)W1)[t];
    if (t < 80) ((float4*)w2_s)[t] = ((const float4*)W2)[t];
    if (t < 32) b1_s[t] = b1[t];
    if (t < 10) b2_s[t] = b2[t];
    if (t < 24) {
        int u = t / 3, l2 = t % 3;
        float q0 = qw[u * 9 + l2 * 3 + 0];
        float q1 = qw[u * 9 + l2 * 3 + 1];
        float q2 = qw[u * 9 + l2 * 3 + 2];
        rot_s[u][l2][0] = cosf(q0);        rot_s[u][l2][1] = sinf(q0);
        rot_s[u][l2][2] = cosf(0.5f * q1); rot_s[u][l2][3] = sinf(0.5f * q1);
        rot_s[u][l2][4] = cosf(q2);        rot_s[u][l2][5] = sinf(q2);
    }
    // Wp frags with the SAME permuted element order: e0..3 <- k=kb*4.., e4..7 <- k=16+kb*4..
    #pragma unroll
    for (int ff = 0; ff < 2; ++ff) {
        int f = t + ff * 256;
        int jc2 = f & 15, kb2 = (f >> 4) & 3, s2 = f >> 6;
        const float* wp = Wp + jc2 * 256 + s2 * 32 + kb2 * 4;
        float4 p0 = *(const float4*)wp;
        float4 p1 = *(const float4*)(wp + 16);
        Frag h, lo2;
        cvt8(p0, p1, h, lo2);
        ((short8*)whi)[f] = h.v;
        ((short8*)wlo)[f] = lo2.v;
    }
    __syncthreads();   // only barrier in the kernel

    const float bpj  = bp[jc];
    const int   srow = l >> 2;
    const int   s4   = l & 3;
    const short8* whi_f = (const short8*)whi;
    const short8* wlo_f = (const short8*)wlo;

    auto do_tile = [&](const float* xpn, int tile, bool refill) {
        f32x4 accm = {bpj, bpj, bpj, bpj};
        f32x4 accc = {0.0f, 0.0f, 0.0f, 0.0f};

        // 8 static K-steps; each consumes its slot, then refills it from next tile
        #define STEP(S, XA, XB)                                                     \
        {                                                                           \
            Frag ah; cvt_hi(XA, XB, ah);                                            \
            if (refill) {                                                           \
                XA = *(const float4*)(xpn + (S) * 32);                              \
                XB = *(const float4*)(xpn + (S) * 32 + 16);                         \
            }                                                                       \
            Frag bh, bl;                                                            \
            bh.v = whi_f[((S) * 4 + kbi) * 16 + jc];                                \
            bl.v = wlo_f[((S) * 4 + kbi) * 16 + jc];                                \
            accm = __builtin_amdgcn_mfma_f32_16x16x32_bf16(ah.v, bh.v, accm, 0, 0, 0); \
            accc = __builtin_amdgcn_mfma_f32_16x16x32_bf16(ah.v, bl.v, accc, 0, 0, 0); \
        }
        STEP(0, xa0, xb0)
        STEP(1, xa1, xb1)
        STEP(2, xa2, xb2)
        STEP(3, xa3, xb3)
        STEP(4, xa4, xb4)
        STEP(5, xa5, xb5)
        STEP(6, xa6, xb6)
        STEP(7, xa7, xb7)
        #undef STEP

        // ---- transpose C[row=kbi*4+r][col=jc] via wave-private LDS ----
        #pragma unroll
        for (int r = 0; r < 4; ++r)
            proj_s[w][(kbi * 4 + r) * 17 + jc] = accm[r] + accc[r];

        float4 pv = *(const float4*)&proj_s[w][srow * 17 + s4 * 4];

        // ---- unit-split circuit: 4 lanes/row, 2 units each ----
        float qv[2];
        #pragma unroll
        for (int uu = 0; uu < 2; ++uu) {
            const int u = 2 * s4 + uu;
            float p0 = (uu == 0) ? pv.x : pv.z;
            float p1 = (uu == 0) ? pv.y : pv.w;
            float th0 = fast_tanh(p0);
            float th1 = fast_tanh(p1);
            float c  = __cosf(0.5f * PI_F * th0);
            float s  = __sinf(0.5f * PI_F * th0);
            float zr = __cosf(PI_F * th1);
            float zi = __sinf(PI_F * th1);

            float ar = c, ai = 0.0f, br = s, bi = 0.0f;
            #pragma unroll
            for (int l2 = 0; l2 < 3; ++l2) {
                if (l2 > 0) {
                    float nar = c * ar - s * br, nai = c * ai - s * bi;
                    float nbr = s * ar + c * br, nbi = s * ai + c * bi;
                    ar = nar; ai = nai; br = nbr; bi = nbi;
                }
                float e0r = rot_s[u][l2][0], e0i = rot_s[u][l2][1];
                float p2r = zr * e0r - zi * e0i;
                float p2q = zr * e0i + zi * e0r;
                float nbr = br * p2r - bi * p2q, nbi = br * p2q + bi * p2r;
                br = nbr; bi = nbi;
                float c1 = rot_s[u][l2][2], s1 = rot_s[u][l2][3];
                float tar = c1 * ar - s1 * br, tai = c1 * ai - s1 * bi;
                float tbr = s1 * ar + c1 * br, tbi = s1 * ai + c1 * bi;
                ar = tar; ai = tai; br = tbr; bi = tbi;
                if (l2 < 2) {
                    float e2r = rot_s[u][l2][4], e2i = rot_s[u][l2][5];
                    float ubr = br * e2r - bi * e2i, ubi = br * e2i + bi * e2r;
                    br = ubr; bi = ubi;
                }
            }
            qv[uu] = (ar * ar + ai * ai) - (br * br + bi * bi);
        }

        float* qb = &qbuf[w][srow][0];
        *(float2*)(qb + 2 * s4) = make_float2(qv[0], qv[1]);
        float4 qa  = *(const float4*)(qb + 0);
        float4 qbv = *(const float4*)(qb + 4);

        // ---- head: lane covers j = s4*8..s4*8+7, 4-lane reduce ----
        float ov[10];
        #pragma unroll
        for (int c2 = 0; c2 < 10; ++c2) ov[c2] = 0.0f;
        #pragma unroll
        for (int jj = 0; jj < 8; ++jj) {
            const int j = s4 * 8 + jj;
            float h = b1_s[j];
            h = fmaf(qa.x,  w1_s[j * 8 + 0], h);
            h = fmaf(qa.y,  w1_s[j * 8 + 1], h);
            h = fmaf(qa.z,  w1_s[j * 8 + 2], h);
            h = fmaf(qa.w,  w1_s[j * 8 + 3], h);
            h = fmaf(qbv.x, w1_s[j * 8 + 4], h);
            h = fmaf(qbv.y, w1_s[j * 8 + 5], h);
            h = fmaf(qbv.z, w1_s[j * 8 + 6], h);
            h = fmaf(qbv.w, w1_s[j * 8 + 7], h);
            h = fmaxf(h, 0.0f);
            #pragma unroll
            for (int c2 = 0; c2 < 10; ++c2) ov[c2] = fmaf(h, w2_s[c2 * 32 + j], ov[c2]);
        }
        #pragma unroll
        for (int c2 = 0; c2 < 10; ++c2) {
            ov[c2] += __shfl_xor(ov[c2], 1);
            ov[c2] += __shfl_xor(ov[c2], 2);
            ov[c2] += b2_s[c2];
        }

        const int orow = tile * 16 + srow;
        if (orow < nrows) {
            float2* op = (float2*)(out + (size_t)orow * 10);
            float lo = (s4 == 0) ? ov[0] : (s4 == 1) ? ov[2] : (s4 == 2) ? ov[4] : ov[6];
            float hi = (s4 == 0) ? ov[1] : (s4 == 1) ? ov[3] : (s4 == 2) ? ov[5] : ov[7];
            op[s4] = make_float2(lo, hi);
            if (s4 == 0) op[4] = make_float2(ov[8], ov[9]);
        }
    };

    // fresh stream active during tiles 0-2; only tile 3 is uncovered
    do_tile(xp1, tile0 + 0, true);
    do_tile(xp2, tile0 + 1, true);
    do_tile(xp3, tile0 + 2, true);
    do_tile(xp3, tile0 + 3, false);
}

extern "C" void kernel_launch(void* const* d_in, const int* in_sizes, int n_in,
                              void* d_out, int out_size, void* d_ws, size_t ws_size,
                              hipStream_t stream) {
    const float* x  = (const float*)d_in[0];
    const float* Wp = (const float*)d_in[1];
    const float* bp = (const float*)d_in[2];
    const float* qw = (const float*)d_in[3];
    const float* W1 = (const float*)d_in[4];
    const float* b1 = (const float*)d_in[5];
    const float* W2 = (const float*)d_in[6];
    const float* b2 = (const float*)d_in[7];
    float* out = (float*)d_out;

    const int nrows = in_sizes[0] / 256;
    const int rows_per_block = 16 * TILES * 4;   // 256
    const int nblocks = (nrows + rows_per_block - 1) / rows_per_block;
    sqru_fused_kernel<<<nblocks, TB, 0, stream>>>(x, Wp, bp, qw, W1, b1, W2, b2, out, nrows);
}

// Round 16
// 32.036 us; speedup vs baseline: 1.1544x; 1.0748x over previous
//
#include <hip/hip_runtime.h>
#include <hip/hip_bf16.h>
#include <math.h>

#define TB 256
#define TILES 2
#define PI_F 3.14159265358979323846f

typedef __attribute__((ext_vector_type(8))) short short8;
typedef __attribute__((ext_vector_type(4))) float f32x4;

union Frag { short8 v; ushort u[8]; uint w[4]; };

__device__ __forceinline__ uint pk2(float a, float b) {
    union { __hip_bfloat162 h; uint u; } cv;
    cv.h = __float22bfloat162_rn(make_float2(a, b));   // packed RNE cvt
    return cv.u;
}

// x path: hi-only bf16 (4 packed cvts per 8 floats)
__device__ __forceinline__ void cvt_hi(const float4& p0, const float4& p1, Frag& hi) {
    hi.w[0] = pk2(p0.x, p0.y); hi.w[1] = pk2(p0.z, p0.w);
    hi.w[2] = pk2(p1.x, p1.y); hi.w[3] = pk2(p1.z, p1.w);
}

// Wp path (one-time): hi + residual lo
__device__ __forceinline__ void cvt8(const float4& p0, const float4& p1, Frag& hi, Frag& lo) {
    float f[8] = {p0.x, p0.y, p0.z, p0.w, p1.x, p1.y, p1.z, p1.w};
    #pragma unroll
    for (int e = 0; e < 4; ++e) hi.w[e] = pk2(f[2 * e], f[2 * e + 1]);
    #pragma unroll
    for (int e = 0; e < 4; ++e) {
        float r0 = f[2 * e]     - __uint_as_float(hi.w[e] << 16);
        float r1 = f[2 * e + 1] - __uint_as_float(hi.w[e] & 0xffff0000u);
        lo.w[e] = pk2(r0, r1);
    }
}

__device__ __forceinline__ float fast_tanh(float p) {
    float t = __expf(2.0f * p);
    return 1.0f - __fdividef(2.0f, t + 1.0f);
}

__global__ __launch_bounds__(TB, 3) void sqru_fused_kernel(
    const float* __restrict__ x, const float* __restrict__ Wp,
    const float* __restrict__ bp, const float* __restrict__ qw,
    const float* __restrict__ W1, const float* __restrict__ b1,
    const float* __restrict__ W2, const float* __restrict__ b2,
    float* __restrict__ out, int nrows)
{
    __shared__ ushort whi[512 * 8];        // 8 KB Wp hi frags [(s*4+kbi)*16+jc]
    __shared__ ushort wlo[512 * 8];        // 8 KB Wp lo frags
    __shared__ float  proj_s[4][16 * 17];  // wave-private transpose
    __shared__ float  qbuf[4][16][8];
    __shared__ float  w1_s[32 * 8];
    __shared__ float  w2_s[10 * 32];
    __shared__ float  b1_s[32];
    __shared__ float  b2_s[10];
    __shared__ float  rot_s[8][3][6];

    const int t   = threadIdx.x;
    const int w   = t >> 6;
    const int l   = t & 63;
    const int jc  = l & 15;     // M-row (batch row) and N-col (proj out) index
    const int kbi = l >> 4;     // K sub-group
    const int gw  = blockIdx.x * 4 + w;
    const int tile0 = gw * TILES;

    int r0 = tile0 * 16 + jc;       if (r0 >= nrows) r0 = nrows - 1;
    int r1 = (tile0 + 1) * 16 + jc; if (r1 >= nrows) r1 = nrows - 1;
    // FULL-LINE mapping: lane (jc,kbi) reads 16B at row*1KB + s*128 + kbi*16 (and +64)
    const float* xp0 = x + (size_t)r0 * 256 + kbi * 4;
    const float* xp1 = x + (size_t)r1 * 256 + kbi * 4;

    // ---- ring prologue: ALL of tile0 (8 K-steps) in flight before staging ----
    float4 xa0 = *(const float4*)(xp0 +   0), xb0 = *(const float4*)(xp0 +  16);
    float4 xa1 = *(const float4*)(xp0 +  32), xb1 = *(const float4*)(xp0 +  48);
    float4 xa2 = *(const float4*)(xp0 +  64), xb2 = *(const float4*)(xp0 +  80);
    float4 xa3 = *(const float4*)(xp0 +  96), xb3 = *(const float4*)(xp0 + 112);
    float4 xa4 = *(const float4*)(xp0 + 128), xb4 = *(const float4*)(xp0 + 144);
    float4 xa5 = *(const float4*)(xp0 + 160), xb5 = *(const float4*)(xp0 + 176);
    float4 xa6 = *(const float4*)(xp0 + 192), xb6 = *(const float4*)(xp0 + 208);
    float4 xa7 = *(const float4*)(xp0 + 224), xb7 = *(const float4*)(xp0 + 240);

    // ---- one-time weight staging ----
    if (t < 64) ((float4*)w1_s)[t] = ((const float4*)W1)[t];
    if (t < 80) ((float4*)w2_s)[t] = ((const float4*)W2)[t];
    if (t < 32) b1_s[t] = b1[t];
    if (t < 10) b2_s[t] = b2[t];
    if (t < 24) {
        int u = t / 3, l2 = t % 3;
        float q0 = qw[u * 9 + l2 * 3 + 0];
        float q1 = qw[u * 9 + l2 * 3 + 1];
        float q2 = qw[u * 9 + l2 * 3 + 2];
        rot_s[u][l2][0] = cosf(q0);        rot_s[u][l2][1] = sinf(q0);
        rot_s[u][l2][2] = cosf(0.5f * q1); rot_s[u][l2][3] = sinf(0.5f * q1);
        rot_s[u][l2][4] = cosf(q2);        rot_s[u][l2][5] = sinf(q2);
    }
    // Wp frags with the SAME permuted element order: e0..3 <- k=kb*4.., e4..7 <- k=16+kb*4..
    #pragma unroll
    for (int ff = 0; ff < 2; ++ff) {
        int f = t + ff * 256;
        int jc2 = f & 15, kb2 = (f >> 4) & 3, s2 = f >> 6;
        const float* wp = Wp + jc2 * 256 + s2 * 32 + kb2 * 4;
        float4 p0 = *(const float4*)wp;
        float4 p1 = *(const float4*)(wp + 16);
        Frag h, lo2;
        cvt8(p0, p1, h, lo2);
        ((short8*)whi)[f] = h.v;
        ((short8*)wlo)[f] = lo2.v;
    }
    __syncthreads();   // only barrier in the kernel

    const float bpj  = bp[jc];
    const int   srow = l >> 2;
    const int   s4   = l & 3;
    const short8* whi_f = (const short8*)whi;
    const short8* wlo_f = (const short8*)wlo;

    auto do_tile = [&](const float* xpn, int tile, bool refill) {
        f32x4 accm = {bpj, bpj, bpj, bpj};
        f32x4 accc = {0.0f, 0.0f, 0.0f, 0.0f};

        // 8 static K-steps; each consumes its slot, then refills it from next tile
        #define STEP(S, XA, XB)                                                     \
        {                                                                           \
            Frag ah; cvt_hi(XA, XB, ah);                                            \
            if (refill) {                                                           \
                XA = *(const float4*)(xpn + (S) * 32);                              \
                XB = *(const float4*)(xpn + (S) * 32 + 16);                         \
            }                                                                       \
            Frag bh, bl;                                                            \
            bh.v = whi_f[((S) * 4 + kbi) * 16 + jc];                                \
            bl.v = wlo_f[((S) * 4 + kbi) * 16 + jc];                                \
            accm = __builtin_amdgcn_mfma_f32_16x16x32_bf16(ah.v, bh.v, accm, 0, 0, 0); \
            accc = __builtin_amdgcn_mfma_f32_16x16x32_bf16(ah.v, bl.v, accc, 0, 0, 0); \
        }
        STEP(0, xa0, xb0)
        STEP(1, xa1, xb1)
        STEP(2, xa2, xb2)
        STEP(3, xa3, xb3)
        STEP(4, xa4, xb4)
        STEP(5, xa5, xb5)
        STEP(6, xa6, xb6)
        STEP(7, xa7, xb7)
        #undef STEP

        // ---- transpose C[row=kbi*4+r][col=jc] via wave-private LDS ----
        #pragma unroll
        for (int r = 0; r < 4; ++r)
            proj_s[w][(kbi * 4 + r) * 17 + jc] = accm[r] + accc[r];

        float4 pv = *(const float4*)&proj_s[w][srow * 17 + s4 * 4];

        // ---- unit-split circuit: 4 lanes/row, 2 units each ----
        float qv[2];
        #pragma unroll
        for (int uu = 0; uu < 2; ++uu) {
            const int u = 2 * s4 + uu;
            float p0 = (uu == 0) ? pv.x : pv.z;
            float p1 = (uu == 0) ? pv.y : pv.w;
            float th0 = fast_tanh(p0);
            float th1 = fast_tanh(p1);
            float c  = __cosf(0.5f * PI_F * th0);
            float s  = __sinf(0.5f * PI_F * th0);
            float zr = __cosf(PI_F * th1);
            float zi = __sinf(PI_F * th1);

            float ar = c, ai = 0.0f, br = s, bi = 0.0f;
            #pragma unroll
            for (int l2 = 0; l2 < 3; ++l2) {
                if (l2 > 0) {
                    float nar = c * ar - s * br, nai = c * ai - s * bi;
                    float nbr = s * ar + c * br, nbi = s * ai + c * bi;
                    ar = nar; ai = nai; br = nbr; bi = nbi;
                }
                float e0r = rot_s[u][l2][0], e0i = rot_s[u][l2][1];
                float p2r = zr * e0r - zi * e0i;
                float p2q = zr * e0i + zi * e0r;
                float nbr = br * p2r - bi * p2q, nbi = br * p2q + bi * p2r;
                br = nbr; bi = nbi;
                float c1 = rot_s[u][l2][2], s1 = rot_s[u][l2][3];
                float tar = c1 * ar - s1 * br, tai = c1 * ai - s1 * bi;
                float tbr = s1 * ar + c1 * br, tbi = s1 * ai + c1 * bi;
                ar = tar; ai = tai; br = tbr; bi = tbi;
                if (l2 < 2) {
                    float e2r = rot_s[u][l2][4], e2i = rot_s[u][l2][5];
                    float ubr = br * e2r - bi * e2i, ubi = br * e2i + bi * e2r;
                    br = ubr; bi = ubi;
                }
            }
            qv[uu] = (ar * ar + ai * ai) - (br * br + bi * bi);
        }

        float* qb = &qbuf[w][srow][0];
        *(float2*)(qb + 2 * s4) = make_float2(qv[0], qv[1]);
        float4 qa  = *(const float4*)(qb + 0);
        float4 qbv = *(const float4*)(qb + 4);

        // ---- head: lane covers j = s4*8..s4*8+7, 4-lane reduce ----
        float ov[10];
        #pragma unroll
        for (int c2 = 0; c2 < 10; ++c2) ov[c2] = 0.0f;
        #pragma unroll
        for (int jj = 0; jj < 8; ++jj) {
            const int j = s4 * 8 + jj;
            float h = b1_s[j];
            h = fmaf(qa.x,  w1_s[j * 8 + 0], h);
            h = fmaf(qa.y,  w1_s[j * 8 + 1], h);
            h = fmaf(qa.z,  w1_s[j * 8 + 2], h);
            h = fmaf(qa.w,  w1_s[j * 8 + 3], h);
            h = fmaf(qbv.x, w1_s[j * 8 + 4], h);
            h = fmaf(qbv.y, w1_s[j * 8 + 5], h);
            h = fmaf(qbv.z, w1_s[j * 8 + 6], h);
            h = fmaf(qbv.w, w1_s[j * 8 + 7], h);
            h = fmaxf(h, 0.0f);
            #pragma unroll
            for (int c2 = 0; c2 < 10; ++c2) ov[c2] = fmaf(h, w2_s[c2 * 32 + j], ov[c2]);
        }
        #pragma unroll
        for (int c2 = 0; c2 < 10; ++c2) {
            ov[c2] += __shfl_xor(ov[c2], 1);
            ov[c2] += __shfl_xor(ov[c2], 2);
            ov[c2] += b2_s[c2];
        }

        const int orow = tile * 16 + srow;
        if (orow < nrows) {
            float2* op = (float2*)(out + (size_t)orow * 10);
            float lo = (s4 == 0) ? ov[0] : (s4 == 1) ? ov[2] : (s4 == 2) ? ov[4] : ov[6];
            float hi = (s4 == 0) ? ov[1] : (s4 == 1) ? ov[3] : (s4 == 2) ? ov[5] : ov[7];
            op[s4] = make_float2(lo, hi);
            if (s4 == 0) op[4] = make_float2(ov[8], ov[9]);
        }
    };

    do_tile(xp1, tile0, true);        // compute tile0, stream in tile1 behind it
    do_tile(xp1, tile0 + 1, false);   // compute tile1, no refill
}

extern "C" void kernel_launch(void* const* d_in, const int* in_sizes, int n_in,
                              void* d_out, int out_size, void* d_ws, size_t ws_size,
                              hipStream_t stream) {
    const float* x  = (const float*)d_in[0];
    const float* Wp = (const float*)d_in[1];
    const float* bp = (const float*)d_in[2];
    const float* qw = (const float*)d_in[3];
    const float* W1 = (const float*)d_in[4];
    const float* b1 = (const float*)d_in[5];
    const float* W2 = (const float*)d_in[6];
    const float* b2 = (const float*)d_in[7];
    float* out = (float*)d_out;

    const int nrows = in_sizes[0] / 256;
    const int rows_per_block = 16 * TILES * 4;   // 128
    const int nblocks = (nrows + rows_per_block - 1) / rows_per_block;
    sqru_fused_kernel<<<nblocks, TB, 0, stream>>>(x, Wp, bp, qw, W1, b1, W2, b2, out, nrows);
}